// Round 11
// baseline (414.509 us; speedup 1.0000x reference)
//
#include <hip/hip_runtime.h>
#include <math.h>

#define B_    128
#define T_    100
#define TPAD  104
#define CB_   4
#define EMB_  128
#define NROW  39936          // 3*128*104 padded rows (all 3 segments)
#define ZOFF  131072         // zero-row offset in embB (shorts)

typedef __attribute__((ext_vector_type(8))) short short8;
typedef __attribute__((ext_vector_type(4))) short short4v;
typedef __attribute__((ext_vector_type(4))) float f32x4;

__device__ __forceinline__ short f2bf(float x) {
  unsigned u = __builtin_bit_cast(unsigned, x);
  u += 0x7fffu + ((u >> 16) & 1u);
  return (short)(u >> 16);
}
__device__ __forceinline__ float bf2f(short s) {
  unsigned u = ((unsigned)(unsigned short)s) << 16;
  return __builtin_bit_cast(float, u);
}

#define GLOAD_LDS(g, l) __builtin_amdgcn_global_load_lds( \
    (const __attribute__((address_space(1))) void*)(g),   \
    (__attribute__((address_space(3))) void*)(l), 16, 0, 0)

#define MFMA16(a, b, c) __builtin_amdgcn_mfma_f32_16x16x32_bf16(a, b, c, 0, 0, 0)
#define SWZ(row, slot) (((slot) + ((row) >> 1)) & 3)

// vmcnt(0) drain + raw barrier + scheduler pin (dbuf step boundary)
#define STEP_SYNC() do {                                   \
    asm volatile("s_waitcnt vmcnt(0)" ::: "memory");       \
    __builtin_amdgcn_s_barrier();                          \
    __builtin_amdgcn_sched_barrier(0);                     \
  } while (0)

// ================ mega-prep: guards + embB + weights + cbsq + pooled-zero ================
// flat ids: [0,1024) Y-guards; [..,132096) embB; [..,132224) zero-row; [..,1705088) conv W;
// [..,1836160) c3wB; [..,2098304) cbkB; [..,5244032) fc1wB; [..,5506176) fc2wB;
// [..,6292608) SB; [..,7865472) pooled-zero.  blocks [30724,32772) d2w transpose;
// [32772,33028) cbsq.  grid = 33028.
__global__ void k_prep(const float* __restrict__ emb,
                       const float* __restrict__ c1w, const float* __restrict__ c2w,
                       const float* __restrict__ c3w, const float* __restrict__ cbk,
                       const float* __restrict__ fc1w, const float* __restrict__ fc2w,
                       const float* __restrict__ d1w, const float* __restrict__ d2w,
                       short* __restrict__ YbS, short* __restrict__ embB,
                       short* __restrict__ Wb1, short* __restrict__ Wb2,
                       short* __restrict__ c3wB, short* __restrict__ cbkB,
                       short* __restrict__ fc1wB, short* __restrict__ fc2wB,
                       short* __restrict__ SB, short* __restrict__ d2wTB,
                       float* __restrict__ cbsq, float* __restrict__ pooled) {
  __shared__ float tile[32][33];
  int bid = blockIdx.x;
  int id = bid * 256 + threadIdx.x;
  if (bid < 30724) {
    if (id < 1024) {
      int row = id >> 9, c = id & 511;
      long off = row ? ((long)(NROW + 1) * 512 + c) : c;
      YbS[off] = 0;
    } else if (id < 132096) {
      int l = id - 1024;
      embB[l] = f2bf(emb[l]);
    } else if (id < 132224) {
      embB[ZOFF + (id - 132096)] = 0;
    } else if (id < 1705088) {
      int local = id - 132224;
      const float* w = (local < 786432) ? c1w : c2w;
      short* o = (local < 786432) ? Wb1 : Wb2;
      int l2 = (local < 786432) ? local : local - 786432;
      int i = l2 & 511, oo = (l2 >> 9) & 511, tap = l2 >> 18;
      o[l2] = f2bf(w[oo * 1536 + i * 3 + tap]);
    } else if (id < 1836160) {
      int l = id - 1705088;
      c3wB[l] = f2bf(c3w[l]);
    } else if (id < 2098304) {
      int l = id - 1836160;
      cbkB[l] = f2bf(cbk[l]);
    } else if (id < 5244032) {
      int l = id - 2098304;
      fc1wB[l] = f2bf(fc1w[l]);
    } else if (id < 5506176) {
      int l = id - 5244032;
      fc2wB[l] = f2bf(fc2w[l]);
    } else if (id < 6292608) {
      int l = id - 5506176;          // 3*512*512
      int i = l & 511, o = (l >> 9) & 511, cls = l >> 18;
      const float* w = d1w + (i * 512 + o) * 3;
      float v;
      if (cls == 0)      v = w[0] + w[1];
      else if (cls == 1) v = w[0] + w[1] + w[2];
      else               v = w[1] + w[2];
      SB[(cls * 512 + o) * 512 + i] = f2bf(v);
    } else {
      pooled[id - 6292608] = 0.f;    // 1,572,864 exact
    }
  } else if (bid < 32772) {
    int blk = bid - 30724;            // 0..2047
    int bx = blk & 127, by = blk >> 7;
    int tx = threadIdx.x & 31, ty = threadIdx.x >> 5;
    #pragma unroll
    for (int j = 0; j < 32; j += 8)
      tile[ty + j][tx] = d2w[(by * 32 + ty + j) * 4096 + bx * 32 + tx];
    __syncthreads();
    #pragma unroll
    for (int j = 0; j < 32; j += 8)
      d2wTB[(bx * 32 + ty + j) * 512 + by * 32 + tx] = f2bf(tile[tx][ty + j]);
  } else {
    int idx = (bid - 32772) * 256 + threadIdx.x;   // 0..65535
    int row = idx >> 6, lane = threadIdx.x & 63;
    float4 v = *(const float4*)&cbk[row * 256 + lane * 4];
    float s = v.x * v.x + v.y * v.y + v.z * v.z + v.w * v.w;
    #pragma unroll
    for (int m = 1; m < 64; m <<= 1) s += __shfl_xor(s, m);
    if (lane == 0) cbsq[row] = s;
  }
}

// ================ conv1 with fused embedding gather (bf16 MFMA, LDS double-buffered) ================
__global__ __launch_bounds__(256) void k_conv1_embed(const int* __restrict__ tok0,
                                                     const int* __restrict__ tok1,
                                                     const int* __restrict__ tok2,
                                                     const short* __restrict__ embB,
                                                     const short* __restrict__ Wb,
                                                     const float* __restrict__ bias,
                                                     short* __restrict__ Y) {
  __shared__ short sm[2][16896];
  int r0 = blockIdx.y * 128;
  int o0 = blockIdx.x * 128;
  int tid = threadIdx.x;
  int lane = tid & 63, wid = tid >> 6;
  int wm = wid >> 1, wn = wid & 1;
  int ls = lane >> 4, lr = lane & 15;
  int g = ((lane & 3) - ((lane >> 3) & 3)) & 3;

  int toff[3][4];
  #pragma unroll
  for (int i = 0; i < 3; ++i) {
    int q = wid + 4 * i;
    if (q < 9) {
      int rr = r0 - 1 + 16 * q + (lane >> 2);
      bool ok = (rr >= 0) && (rr < NROW);
      int sb = ok ? (rr / 104) : 0;
      int t = rr - sb * 104;
      ok = ok && (t < T_);
      int b = sb & 127, s = sb >> 7;
      const int* tokp = (s == 0) ? tok0 : (s == 1) ? tok1 : tok2;
      if (ok) {
        int4 tv = *(const int4*)&tokp[(b * T_ + t) * CB_];
        toff[i][0] = tv.x * EMB_; toff[i][1] = tv.y * EMB_;
        toff[i][2] = tv.z * EMB_; toff[i][3] = tv.w * EMB_;
      } else {
        toff[i][0] = toff[i][1] = toff[i][2] = toff[i][3] = ZOFF;
      }
    }
  }
  const short* gpw[9];
  #pragma unroll
  for (int i = 0; i < 9; ++i) {
    int q = wid + 4 * i;
    if (q >= 9 && q < 33) {
      int b = q - 9, tap = b >> 3, jj = b & 7;
      gpw[i] = Wb + (long)(tap * 512 + o0 + 16 * jj) * 512 + (long)(lane >> 2) * 512 + g * 8;
    }
  }

  #pragma unroll
  for (int i = 0; i < 3; ++i) {
    int q = wid + 4 * i;
    if (q < 9) GLOAD_LDS(embB + toff[i][0] + g * 8, &sm[0][q * 512]);
  }
  #pragma unroll
  for (int i = 0; i < 9; ++i) {
    int q = wid + 4 * i;
    if (q >= 9 && q < 33) { GLOAD_LDS(gpw[i], &sm[0][q * 512]); gpw[i] += 32; }
  }
  STEP_SYNC();

  f32x4 acc[4][4] = {};
  #pragma unroll
  for (int u = 0; u < 16; ++u) {          // u = cb*4 + kk
    const int cur = u & 1;
    if (u < 15) {
      const int cb2 = (u + 1) >> 2, kk2 = (u + 1) & 3;
      #pragma unroll
      for (int i = 0; i < 3; ++i) {
        int q = wid + 4 * i;
        if (q < 9) GLOAD_LDS(embB + toff[i][cb2] + kk2 * 32 + g * 8, &sm[cur ^ 1][q * 512]);
      }
      #pragma unroll
      for (int i = 0; i < 9; ++i) {
        int q = wid + 4 * i;
        if (q >= 9 && q < 33) { GLOAD_LDS(gpw[i], &sm[cur ^ 1][q * 512]); gpw[i] += 32; }
      }
    }
    const short8* A8 = (const short8*)sm[cur];
    const short8* B8 = (const short8*)(sm[cur] + 4608);
    #pragma unroll
    for (int tap = 0; tap < 3; ++tap) {
      short8 a[4], b[4];
      #pragma unroll
      for (int m = 0; m < 4; ++m) {
        int row = wm * 64 + m * 16 + lr + tap;
        a[m] = A8[row * 4 + SWZ(row, ls)];
      }
      #pragma unroll
      for (int n = 0; n < 4; ++n) {
        int row = wn * 64 + n * 16 + lr;
        b[n] = B8[(tap * 128 + row) * 4 + SWZ(row, ls)];
      }
      #pragma unroll
      for (int m = 0; m < 4; ++m)
        #pragma unroll
        for (int n = 0; n < 4; ++n)
          acc[m][n] = MFMA16(a[m], b[n], acc[m][n]);
    }
    STEP_SYNC();
  }
  #pragma unroll
  for (int m = 0; m < 4; ++m) {
    #pragma unroll
    for (int n = 0; n < 4; ++n) {
      int col = o0 + wn * 64 + n * 16 + lr;
      float bv = bias[col];
      #pragma unroll
      for (int j = 0; j < 4; ++j) {
        int r = r0 + wm * 64 + m * 16 + ls * 4 + j;
        int t = r % TPAD;
        float v = (t < T_) ? fmaxf(acc[m][n][j] + bv, 0.f) : 0.f;
        Y[(long)r * 512 + col] = f2bf(v);
      }
    }
  }
}

// ================ conv2 with fused adaptive-pool accumulate (bf16 MFMA, dbuf) ================
// Output never materialized: relu(acc+bias)/13 atomically accumulated into pooled bins.
__global__ __launch_bounds__(256) void k_conv2_pool(const short* __restrict__ X,
                                                    const short* __restrict__ Wb,
                                                    const float* __restrict__ bias,
                                                    float* __restrict__ pooled) {
  __shared__ short sm[2][16896];
  int r0 = blockIdx.y * 128;
  int o0 = blockIdx.x * 128;
  int tid = threadIdx.x;
  int lane = tid & 63, wid = tid >> 6;
  int wm = wid >> 1, wn = wid & 1;
  int ls = lane >> 4, lr = lane & 15;
  int g = ((lane & 3) - ((lane >> 3) & 3)) & 3;
  long laneoff = (long)(lane >> 2) * 512 + g * 8;

  const short* gp[9];
  #pragma unroll
  for (int i = 0; i < 9; ++i) {
    int q = wid + 4 * i;
    if (q < 33) {
      long base;
      const short* src;
      if (q < 9) { src = X; base = (long)(r0 - 1 + 16 * q) * 512; }
      else {
        int b = q - 9, tap = b >> 3, j = b & 7;
        src = Wb; base = (long)(tap * 512 + o0 + 16 * j) * 512;
      }
      gp[i] = src + base + laneoff;
    }
  }

  #pragma unroll
  for (int i = 0; i < 9; ++i) {
    int q = wid + 4 * i;
    if (q < 33) { GLOAD_LDS(gp[i], &sm[0][q * 512]); gp[i] += 32; }
  }
  STEP_SYNC();

  f32x4 acc[4][4] = {};
  #pragma unroll
  for (int u = 0; u < 16; ++u) {
    const int cur = u & 1;
    if (u < 15) {
      #pragma unroll
      for (int i = 0; i < 9; ++i) {
        int q = wid + 4 * i;
        if (q < 33) { GLOAD_LDS(gp[i], &sm[cur ^ 1][q * 512]); gp[i] += 32; }
      }
    }
    const short8* A8 = (const short8*)sm[cur];
    const short8* B8 = (const short8*)(sm[cur] + 4608);
    #pragma unroll
    for (int tap = 0; tap < 3; ++tap) {
      short8 a[4], b[4];
      #pragma unroll
      for (int m = 0; m < 4; ++m) {
        int row = wm * 64 + m * 16 + lr + tap;
        a[m] = A8[row * 4 + SWZ(row, ls)];
      }
      #pragma unroll
      for (int n = 0; n < 4; ++n) {
        int row = wn * 64 + n * 16 + lr;
        b[n] = B8[(tap * 128 + row) * 4 + SWZ(row, ls)];
      }
      #pragma unroll
      for (int m = 0; m < 4; ++m)
        #pragma unroll
        for (int n = 0; n < 4; ++n)
          acc[m][n] = MFMA16(a[m], b[n], acc[m][n]);
    }
    STEP_SYNC();
  }
  // ---- fused pool epilogue: t -> bins p in [2t/25, (2t+1)/25] (1 or 2 bins) ----
  #pragma unroll
  for (int m = 0; m < 4; ++m) {
    #pragma unroll
    for (int n = 0; n < 4; ++n) {
      int col = o0 + wn * 64 + n * 16 + lr;
      float bv = bias[col];
      #pragma unroll
      for (int j = 0; j < 4; ++j) {
        int r = r0 + wm * 64 + m * 16 + ls * 4 + j;
        int sb = r / 104;
        int t = r - sb * 104;
        if (t < T_) {
          float v = fmaxf(acc[m][n][j] + bv, 0.f) * (1.f / 13.f);
          int plo = (2 * t) / 25;
          int phi = (2 * t + 1) / 25;
          atomicAdd(&pooled[(long)(sb * 8 + plo) * 512 + col], v);
          if (phi != plo)
            atomicAdd(&pooled[(long)(sb * 8 + phi) * 512 + col], v);
        }
      }
    }
  }
}

// ================ pooled f32 -> bf16 ================
__global__ void k_poolcvt(const float* __restrict__ pooled, short* __restrict__ pooledB) {
  int id = blockIdx.x * 256 + threadIdx.x;   // 196608 exact
  float4 a0 = *(const float4*)&pooled[(long)id * 8];
  float4 a1 = *(const float4*)&pooled[(long)id * 8 + 4];
  short8 o;
  o[0] = f2bf(a0.x); o[1] = f2bf(a0.y); o[2] = f2bf(a0.z); o[3] = f2bf(a0.w);
  o[4] = f2bf(a1.x); o[5] = f2bf(a1.y); o[6] = f2bf(a1.z); o[7] = f2bf(a1.w);
  ((short8*)pooledB)[id] = o;
}

// ================ bf16 MFMA GEMM (full-K): C(f32) & Cb(bf16) = A@B^T + bias ================
__global__ __launch_bounds__(256) void k_gemm_mfma(const short* __restrict__ A,
                                                   const short* __restrict__ B,
                                                   float* __restrict__ C,
                                                   short* __restrict__ Cb,
                                                   const float* __restrict__ bias,
                                                   int K, int N, int relu) {
  __shared__ short sm[8192];
  int r0 = blockIdx.x * 128;
  int o0 = blockIdx.y * 128;
  int tid = threadIdx.x;
  int lane = tid & 63, wid = tid >> 6;
  int wm = wid >> 1, wn = wid & 1;
  int ls = lane >> 4, lr = lane & 15;
  int g = ((lane & 3) - ((lane >> 3) & 3)) & 3;
  long laneoff = (long)(lane >> 2) * K + g * 8;

  const short* gp[4];
  const short* lp[4];
  #pragma unroll
  for (int i = 0; i < 4; ++i) {
    int q = wid + 4 * i;
    const short* src;
    long base;
    if (q < 8) { src = A; base = (long)(r0 + 16 * q) * K; }
    else       { src = B; base = (long)(o0 + 16 * (q - 8)) * K; }
    gp[i] = src + base + laneoff;
    lp[i] = sm + q * 512;
  }

  f32x4 acc[4][4] = {};
  for (int kc = 0; kc < K; kc += 32) {
    __syncthreads();
    #pragma unroll
    for (int i = 0; i < 4; ++i) {
      GLOAD_LDS(gp[i], lp[i]);
      gp[i] += 32;
    }
    __syncthreads();
    const short8* A8 = (const short8*)sm;
    const short8* B8 = (const short8*)(sm + 4096);
    short8 a[4], b[4];
    #pragma unroll
    for (int m = 0; m < 4; ++m) {
      int row = wm * 64 + m * 16 + lr;
      a[m] = A8[row * 4 + SWZ(row, ls)];
    }
    #pragma unroll
    for (int n = 0; n < 4; ++n) {
      int row = wn * 64 + n * 16 + lr;
      b[n] = B8[row * 4 + SWZ(row, ls)];
    }
    #pragma unroll
    for (int m = 0; m < 4; ++m)
      #pragma unroll
      for (int n = 0; n < 4; ++n)
        acc[m][n] = MFMA16(a[m], b[n], acc[m][n]);
  }
  #pragma unroll
  for (int m = 0; m < 4; ++m) {
    #pragma unroll
    for (int n = 0; n < 4; ++n) {
      int col = o0 + wn * 64 + n * 16 + lr;
      float bv = bias ? bias[col] : 0.f;
      #pragma unroll
      for (int j = 0; j < 4; ++j) {
        int r = r0 + wm * 64 + m * 16 + ls * 4 + j;
        float v = acc[m][n][j] + bv;
        if (relu) v = fmaxf(v, 0.f);
        C[(long)r * N + col] = v;
        if (Cb) Cb[(long)r * N + col] = f2bf(v);
      }
    }
  }
}

// ================ dot GEMM + per-tile argmin partials (K=256) ================
__global__ __launch_bounds__(256) void k_dot_argmin(const short* __restrict__ A,
                                                    const short* __restrict__ B,
                                                    const float* __restrict__ cbsq,
                                                    float* __restrict__ apv,
                                                    int* __restrict__ api) {
  __shared__ short sm[8192];
  __shared__ float svv[128][2];
  __shared__ int sii[128][2];
  const int K = 256;
  int r0 = blockIdx.x * 128;
  int o0 = blockIdx.y * 128;
  int tid = threadIdx.x;
  int lane = tid & 63, wid = tid >> 6;
  int wm = wid >> 1, wn = wid & 1;
  int ls = lane >> 4, lr = lane & 15;
  int g = ((lane & 3) - ((lane >> 3) & 3)) & 3;
  long laneoff = (long)(lane >> 2) * K + g * 8;

  const short* gp[4];
  const short* lp[4];
  #pragma unroll
  for (int i = 0; i < 4; ++i) {
    int q = wid + 4 * i;
    const short* src;
    long base;
    if (q < 8) { src = A; base = (long)(r0 + 16 * q) * K; }
    else       { src = B; base = (long)(o0 + 16 * (q - 8)) * K; }
    gp[i] = src + base + laneoff;
    lp[i] = sm + q * 512;
  }

  f32x4 acc[4][4] = {};
  #pragma unroll
  for (int kc = 0; kc < K; kc += 32) {
    __syncthreads();
    #pragma unroll
    for (int i = 0; i < 4; ++i) {
      GLOAD_LDS(gp[i], lp[i]);
      gp[i] += 32;
    }
    __syncthreads();
    const short8* A8 = (const short8*)sm;
    const short8* B8 = (const short8*)(sm + 4096);
    short8 a[4], b[4];
    #pragma unroll
    for (int m = 0; m < 4; ++m) {
      int row = wm * 64 + m * 16 + lr;
      a[m] = A8[row * 4 + SWZ(row, ls)];
    }
    #pragma unroll
    for (int n = 0; n < 4; ++n) {
      int row = wn * 64 + n * 16 + lr;
      b[n] = B8[row * 4 + SWZ(row, ls)];
    }
    #pragma unroll
    for (int m = 0; m < 4; ++m)
      #pragma unroll
      for (int n = 0; n < 4; ++n)
        acc[m][n] = MFMA16(a[m], b[n], acc[m][n]);
  }
  // ---- argmin epilogue ----
  float cq[4];
  #pragma unroll
  for (int n = 0; n < 4; ++n) cq[n] = cbsq[o0 + wn * 64 + n * 16 + lr];
  #pragma unroll
  for (int m = 0; m < 4; ++m) {
    #pragma unroll
    for (int j = 0; j < 4; ++j) {
      float bv = 3.4e38f; int bi = 0x7fffffff;
      #pragma unroll
      for (int n = 0; n < 4; ++n) {
        int col = o0 + wn * 64 + n * 16 + lr;
        float v = cq[n] - 2.f * acc[m][n][j];
        if (v < bv || (v == bv && col < bi)) { bv = v; bi = col; }
      }
      #pragma unroll
      for (int d = 1; d < 16; d <<= 1) {
        float ov = __shfl_xor(bv, d);
        int oi = __shfl_xor(bi, d);
        if (ov < bv || (ov == bv && oi < bi)) { bv = ov; bi = oi; }
      }
      if (lr == 0) {
        int rl = wm * 64 + m * 16 + ls * 4 + j;
        svv[rl][wn] = bv;
        sii[rl][wn] = bi;
      }
    }
  }
  __syncthreads();
  if (tid < 128) {
    float v0 = svv[tid][0], v1 = svv[tid][1];
    int i0 = sii[tid][0], i1 = sii[tid][1];
    bool t1 = (v1 < v0) || (v1 == v0 && i1 < i0);
    apv[(long)(r0 + tid) * 8 + blockIdx.y] = t1 ? v1 : v0;
    api[(long)(r0 + tid) * 8 + blockIdx.y] = t1 ? i1 : i0;
  }
}

// ================ VQ combine: 8 partials -> argmin; gather + commit ================
__global__ __launch_bounds__(256) void k_vq_combine(const float* __restrict__ apv,
                                                    const int* __restrict__ api,
                                                    const float* __restrict__ ze,
                                                    const float* __restrict__ cb,
                                                    const short* __restrict__ cbkB,
                                                    short* __restrict__ zallB,
                                                    float* __restrict__ commit_part) {
  __shared__ float sv[256];
  __shared__ int ksb;
  int row = blockIdx.x, tid = threadIdx.x;   // row = s*1024 + b*8 + p
  if (tid == 0) {
    float bv = apv[(long)row * 8]; int bi = api[(long)row * 8];
    #pragma unroll
    for (int j = 1; j < 8; ++j) {
      float v = apv[(long)row * 8 + j]; int i = api[(long)row * 8 + j];
      if (v < bv || (v == bv && i < bi)) { bv = v; bi = i; }
    }
    ksb = bi;
  }
  __syncthreads();
  int ks = ksb;
  float zq = cb[ks * 256 + tid];
  float zev = ze[(long)row * 256 + tid];
  int s = row >> 10, bp = row & 1023;
  int b = bp >> 3, p = bp & 7;
  zallB[b * 6144 + s * 2048 + p * 256 + tid] = cbkB[ks * 256 + tid];
  float d = zev - zq;
  sv[tid] = d * d;
  __syncthreads();
  for (int off = 128; off; off >>= 1) { if (tid < off) sv[tid] += sv[tid + off]; __syncthreads(); }
  if (tid == 0) commit_part[row] = sv[0];
}

// ================ bf16 MFMA split-K stage 1: part[bz][M][N] ================
__global__ __launch_bounds__(256) void k_gemm_mfma_sk(const short* __restrict__ A,
                                                      const short* __restrict__ B,
                                                      float* __restrict__ part,
                                                      int M, int N, int K,
                                                      int kchunk, int KS, long bgstride) {
  __shared__ short sm[8192];
  int r0 = blockIdx.x * 128;
  int o0 = blockIdx.y * 128;
  int bz = blockIdx.z;
  int g = bz / KS, zz = bz - g * KS;
  const short* Bg = B + (long)g * bgstride;
  int k0 = zz * kchunk;
  int tid = threadIdx.x;
  int lane = tid & 63, wid = tid >> 6;
  int wm = wid >> 1, wn = wid & 1;
  int ls = lane >> 4, lr = lane & 15;
  int gsl = ((lane & 3) - ((lane >> 3) & 3)) & 3;
  long laneoff = (long)(lane >> 2) * K + gsl * 8 + k0;

  const short* gp[4];
  const short* lp[4];
  #pragma unroll
  for (int i = 0; i < 4; ++i) {
    int q = wid + 4 * i;
    const short* src;
    long base;
    if (q < 8) { src = A;  base = (long)(r0 + 16 * q) * K; }
    else       { src = Bg; base = (long)(o0 + 16 * (q - 8)) * K; }
    gp[i] = src + base + laneoff;
    lp[i] = sm + q * 512;
  }

  f32x4 acc[4][4] = {};
  for (int kc = 0; kc < kchunk; kc += 32) {
    __syncthreads();
    #pragma unroll
    for (int i = 0; i < 4; ++i) {
      GLOAD_LDS(gp[i], lp[i]);
      gp[i] += 32;
    }
    __syncthreads();
    const short8* A8 = (const short8*)sm;
    const short8* B8 = (const short8*)(sm + 4096);
    short8 a[4], b[4];
    #pragma unroll
    for (int m = 0; m < 4; ++m) {
      int row = wm * 64 + m * 16 + lr;
      a[m] = A8[row * 4 + SWZ(row, ls)];
    }
    #pragma unroll
    for (int n = 0; n < 4; ++n) {
      int row = wn * 64 + n * 16 + lr;
      b[n] = B8[row * 4 + SWZ(row, ls)];
    }
    #pragma unroll
    for (int m = 0; m < 4; ++m)
      #pragma unroll
      for (int n = 0; n < 4; ++n)
        acc[m][n] = MFMA16(a[m], b[n], acc[m][n]);
  }
  float* P = part + (long)bz * M * N;
  #pragma unroll
  for (int m = 0; m < 4; ++m) {
    #pragma unroll
    for (int n = 0; n < 4; ++n) {
      int col = o0 + wn * 64 + n * 16 + lr;
      #pragma unroll
      for (int j = 0; j < 4; ++j) {
        int r = r0 + wm * 64 + m * 16 + ls * 4 + j;
        P[(long)r * N + col] = acc[m][n][j];
      }
    }
  }
}

// ================ split-K stage 2 -> bf16 ================
__global__ void k_reduce_bf16(const float* __restrict__ part, short* __restrict__ Cb,
                              const float* __restrict__ bias, int N, int MN,
                              int KS, int relu, int total4) {
  int id = blockIdx.x * 256 + threadIdx.x;
  if (id >= total4) return;
  int e = id * 4;
  int g = e / MN;
  int rem = e - g * MN;
  const float* base = part + (long)g * KS * MN + rem;
  float4 s = *(const float4*)base;
  for (int j = 1; j < KS; ++j) {
    float4 v = *(const float4*)(base + (long)j * MN);
    s.x += v.x; s.y += v.y; s.z += v.z; s.w += v.w;
  }
  int c = rem % N;
  s.x += bias[c]; s.y += bias[c + 1]; s.z += bias[c + 2]; s.w += bias[c + 3];
  if (relu) {
    s.x = fmaxf(s.x, 0.f); s.y = fmaxf(s.y, 0.f);
    s.z = fmaxf(s.z, 0.f); s.w = fmaxf(s.w, 0.f);
  }
  short4v o;
  o[0] = f2bf(s.x); o[1] = f2bf(s.y); o[2] = f2bf(s.z); o[3] = f2bf(s.w);
  *(short4v*)&Cb[(long)g * MN + rem] = o;
}

// ================ fused: logits (single partial) + logsumexp + NLL gather ================
__global__ __launch_bounds__(256) void k_logits_lse_recon(const float* __restrict__ part,
                                                          const float* __restrict__ d2b,
                                                          const int* __restrict__ tok,
                                                          float* __restrict__ rpart2) {
  __shared__ float row[1024];
  __shared__ float sm[256];
  int blk = blockIdx.x;
  int cb_i = blk & 3, b = (blk >> 2) & 127, cls = blk >> 9;
  int m = cls * 128 + b;
  const float* p0 = part + (long)m * 4096 + cb_i * 1024;
  const float* bb = d2b + cb_i * 1024;
  int tid = threadIdx.x;
  float v[4];
  #pragma unroll
  for (int j = 0; j < 4; ++j) {
    int c = tid + 256 * j;
    v[j] = p0[c] + bb[c];
    row[c] = v[j];
  }
  float mx = fmaxf(fmaxf(v[0], v[1]), fmaxf(v[2], v[3]));
  sm[tid] = mx; __syncthreads();
  for (int off = 128; off; off >>= 1) { if (tid < off) sm[tid] = fmaxf(sm[tid], sm[tid + off]); __syncthreads(); }
  float gm = sm[0]; __syncthreads();
  float e = expf(v[0] - gm) + expf(v[1] - gm) + expf(v[2] - gm) + expf(v[3] - gm);
  sm[tid] = e; __syncthreads();
  for (int off = 128; off; off >>= 1) { if (tid < off) sm[tid] += sm[tid + off]; __syncthreads(); }
  float lse = gm + logf(sm[0]);
  __syncthreads();
  float val = 0.f;
  if (cls == 1) {
    if (tid < 98) {
      int tk = tok[(b * T_ + tid + 1) * CB_ + cb_i];
      val = lse - row[tk];
    }
  } else if (tid == 0) {
    int t = (cls == 0) ? 0 : 99;
    int tk = tok[(b * T_ + t) * CB_ + cb_i];
    val = lse - row[tk];
  }
  sm[tid] = val; __syncthreads();
  for (int off = 128; off; off >>= 1) { if (tid < off) sm[tid] += sm[tid + off]; __syncthreads(); }
  if (tid == 0) rpart2[blk] = sm[0];
}

// ================ final ================
__global__ void k_final(const float* __restrict__ rpart2, const float* __restrict__ cpart,
                        float* __restrict__ out) {
  __shared__ float sm[256];
  __shared__ float rs;
  int tid = threadIdx.x;
  float r = 0.f;
  #pragma unroll
  for (int j = 0; j < 6; ++j) r += rpart2[tid + 256 * j];
  sm[tid] = r; __syncthreads();
  for (int off = 128; off; off >>= 1) { if (tid < off) sm[tid] += sm[tid + off]; __syncthreads(); }
  if (tid == 0) rs = sm[0];
  __syncthreads();
  float c = 0.f;
  #pragma unroll
  for (int j = 0; j < 12; ++j) c += cpart[tid + 256 * j];
  sm[tid] = c; __syncthreads();
  for (int off = 128; off; off >>= 1) { if (tid < off) sm[tid] += sm[tid + off]; __syncthreads(); }
  if (tid == 0) out[0] = rs / 51200.f + 0.1f * (sm[0] / 262144.f);
}

extern "C" void kernel_launch(void* const* d_in, const int* in_sizes, int n_in,
                              void* d_out, int out_size, void* d_ws, size_t ws_size,
                              hipStream_t stream) {
  const int*   tok_prev = (const int*)d_in[0];
  const int*   tok_curr = (const int*)d_in[1];
  const int*   tok_next = (const int*)d_in[2];
  const float* emb  = (const float*)d_in[3];
  const float* c1w  = (const float*)d_in[4];
  const float* c1b  = (const float*)d_in[5];
  const float* c2w  = (const float*)d_in[6];
  const float* c2b  = (const float*)d_in[7];
  const float* c3w  = (const float*)d_in[8];
  const float* c3b  = (const float*)d_in[9];
  const float* cbk  = (const float*)d_in[10];
  const float* fc1w = (const float*)d_in[11];
  const float* fc1b = (const float*)d_in[12];
  const float* fc2w = (const float*)d_in[13];
  const float* fc2b = (const float*)d_in[14];
  const float* d1w  = (const float*)d_in[15];
  const float* d1b  = (const float*)d_in[16];
  const float* d2w  = (const float*)d_in[17];
  const float* d2b  = (const float*)d_in[18];

  // ---- workspace layout (f32 word offsets) ----
  float* ws = (float*)d_ws;
  short* YbS = (short*)ws;                          // conv1 output bf16, guard rows
  float* fp  = ws + 10224128;
  short* Wb1    = (short*)fp;                       //   393,216 w
  short* Wb2    = (short*)(fp + 393216);            //   393,216 w
  short* c3wB   = (short*)(fp + 786432);            //    65,536 w
  short* cbkB   = (short*)(fp + 851968);            //   131,072 w
  float* pooled = fp + 983040;                      // 1,572,864 w (f32 bins)
  short* pooledB= (short*)(fp + 2555904);           //   786,432 w
  float* ze     = fp + 3342336;                     //   786,432 w
  short* zeB    = (short*)(fp + 4128768);           //   393,216 w
  short* fc1wB  = (short*)(fp + 4521984);           // 1,572,864 w
  short* fc2wB  = (short*)(fp + 6094848);           //   131,072 w
  short* SB     = (short*)(fp + 6225920);           //   393,216 w
  short* d2wTB  = (short*)(fp + 6619136);           // 1,048,576 w
  float* part   = fp + 7667712;                     // 3,145,728 w (split-K partials)
  float* cbsq   = fp + 10813440;                    //     1,024
  short* zallB  = (short*)(fp + 10814464);          //   393,216 w
  float* cpart  = fp + 11207680;                    //     3,072
  short* h1B    = (short*)(fp + 11210752);          //    32,768 w
  short* h2B    = (short*)(fp + 11243520);          //    32,768 w
  short* h2cB   = (short*)(fp + 11276288);          //    98,304 w
  float* rpart2 = fp + 11374592;                    //     1,536
  float* apv    = fp + 11376128;                    //    24,576
  int*   api    = (int*)(fp + 11400704);            //    24,576
  short* embB   = (short*)(fp + 11425280);          //    65,600 w
  // total ~21.7M words ~87 MB

  const short* Yv = YbS + 512;    // conv1 output rows, row -1 = guard

  // ---- prep (weights, guards, cbsq, pooled zero) ----
  k_prep<<<33028, 256, 0, stream>>>(emb, c1w, c2w, c3w, cbk, fc1w, fc2w, d1w, d2w,
                                    YbS, embB, Wb1, Wb2, c3wB, cbkB, fc1wB, fc2wB,
                                    SB, d2wTB, cbsq, pooled);

  // ---- encoder (all 3 segments batched) ----
  k_conv1_embed<<<dim3(4, 312), 256, 0, stream>>>(tok_prev, tok_curr, tok_next,
                                                  embB, Wb1, c1b, (short*)Yv);
  k_conv2_pool <<<dim3(4, 312), 256, 0, stream>>>(Yv, Wb2, c2b, pooled);
  k_poolcvt    <<<768, 256, 0, stream>>>(pooled, pooledB);
  k_gemm_mfma  <<<dim3(24, 2), 256, 0, stream>>>(pooledB, c3wB, ze, zeB, c3b, 512, 256, 0);
  k_dot_argmin <<<dim3(24, 8), 256, 0, stream>>>(zeB, cbkB, cbsq, apv, api);
  k_vq_combine <<<3072, 256, 0, stream>>>(apv, api, ze, cbk, cbkB, zallB, cpart);

  // ---- decoder: bf16 MFMA split-K ----
  k_gemm_mfma_sk<<<dim3(1, 4, 16), 256, 0, stream>>>(zallB, fc1wB, part, 128, 512, 6144, 384, 16, 0);
  k_reduce_bf16 <<<64, 256, 0, stream>>>(part, h1B, fc1b, 512, 65536, 16, 1, 16384);
  k_gemm_mfma_sk<<<dim3(1, 4, 8), 256, 0, stream>>>(h1B, fc2wB, part, 128, 512, 512, 64, 8, 0);
  k_reduce_bf16 <<<64, 256, 0, stream>>>(part, h2B, fc2b, 512, 65536, 8, 1, 16384);
  k_gemm_mfma_sk<<<dim3(1, 4, 24), 256, 0, stream>>>(h2B, SB, part, 128, 512, 512, 64, 8, 262144);
  k_reduce_bf16 <<<192, 256, 0, stream>>>(part, h2cB, d1b, 512, 65536, 8, 1, 49152);
  k_gemm_mfma_sk<<<dim3(3, 32, 1), 256, 0, stream>>>(h2cB, d2wTB, part, 384, 4096, 512, 512, 1, 0);
  k_logits_lse_recon<<<1536, 256, 0, stream>>>(part, d2b, tok_curr, rpart2);

  k_final<<<1, 256, 0, stream>>>(rpart2, cpart, (float*)d_out);
}

// Round 13
// 259.233 us; speedup vs baseline: 1.5990x; 1.5990x over previous
//
#include <hip/hip_runtime.h>
#include <math.h>

#define B_    128
#define T_    100
#define TPAD  104
#define CB_   4
#define EMB_  128
#define NROW  39936          // 3*128*104 padded rows (all 3 segments)
#define ZOFF  131072         // zero-row offset in embB (shorts)

typedef __attribute__((ext_vector_type(8))) short short8;
typedef __attribute__((ext_vector_type(4))) short short4v;
typedef __attribute__((ext_vector_type(4))) float f32x4;

__device__ __forceinline__ short f2bf(float x) {
  unsigned u = __builtin_bit_cast(unsigned, x);
  u += 0x7fffu + ((u >> 16) & 1u);
  return (short)(u >> 16);
}
__device__ __forceinline__ float bf2f(short s) {
  unsigned u = ((unsigned)(unsigned short)s) << 16;
  return __builtin_bit_cast(float, u);
}

#define GLOAD_LDS(g, l) __builtin_amdgcn_global_load_lds( \
    (const __attribute__((address_space(1))) void*)(g),   \
    (__attribute__((address_space(3))) void*)(l), 16, 0, 0)

#define MFMA16(a, b, c) __builtin_amdgcn_mfma_f32_16x16x32_bf16(a, b, c, 0, 0, 0)
#define SWZ(row, slot) (((slot) + ((row) >> 1)) & 3)

// vmcnt(0) drain + raw barrier + scheduler pin (dbuf step boundary)
#define STEP_SYNC() do {                                   \
    asm volatile("s_waitcnt vmcnt(0)" ::: "memory");       \
    __builtin_amdgcn_s_barrier();                          \
    __builtin_amdgcn_sched_barrier(0);                     \
  } while (0)

// ================ mega-prep: guards + embB + all weight conversions + cbsq ================
__global__ void k_prep(const float* __restrict__ emb,
                       const float* __restrict__ c1w, const float* __restrict__ c2w,
                       const float* __restrict__ c3w, const float* __restrict__ cbk,
                       const float* __restrict__ fc1w, const float* __restrict__ fc2w,
                       const float* __restrict__ d1w, const float* __restrict__ d2w,
                       short* __restrict__ YbS, short* __restrict__ embB,
                       short* __restrict__ Wb1, short* __restrict__ Wb2,
                       short* __restrict__ c3wB, short* __restrict__ cbkB,
                       short* __restrict__ fc1wB, short* __restrict__ fc2wB,
                       short* __restrict__ SB, short* __restrict__ d2wTB,
                       float* __restrict__ cbsq) {
  __shared__ float tile[32][33];
  int bid = blockIdx.x;
  int id = bid * 256 + threadIdx.x;
  if (bid < 24581) {
    if (id < 1024) {
      int row = id >> 9, c = id & 511;
      long off = row ? ((long)(NROW + 1) * 512 + c) : c;
      YbS[off] = 0;
    } else if (id < 132096) {
      int l = id - 1024;
      embB[l] = f2bf(emb[l]);
    } else if (id < 132224) {
      embB[ZOFF + (id - 132096)] = 0;
    } else if (id < 1705088) {
      int local = id - 132224;
      const float* w = (local < 786432) ? c1w : c2w;
      short* o = (local < 786432) ? Wb1 : Wb2;
      int l2 = (local < 786432) ? local : local - 786432;
      int i = l2 & 511, oo = (l2 >> 9) & 511, tap = l2 >> 18;
      o[l2] = f2bf(w[oo * 1536 + i * 3 + tap]);
    } else if (id < 1836160) {
      int l = id - 1705088;
      c3wB[l] = f2bf(c3w[l]);
    } else if (id < 2098304) {
      int l = id - 1836160;
      cbkB[l] = f2bf(cbk[l]);
    } else if (id < 5244032) {
      int l = id - 2098304;
      fc1wB[l] = f2bf(fc1w[l]);
    } else if (id < 5506176) {
      int l = id - 5244032;
      fc2wB[l] = f2bf(fc2w[l]);
    } else if (id < 6292608) {
      int l = id - 5506176;          // 3*512*512
      int i = l & 511, o = (l >> 9) & 511, cls = l >> 18;
      const float* w = d1w + (i * 512 + o) * 3;
      float v;
      if (cls == 0)      v = w[0] + w[1];
      else if (cls == 1) v = w[0] + w[1] + w[2];
      else               v = w[1] + w[2];
      SB[(cls * 512 + o) * 512 + i] = f2bf(v);
    }
  } else if (bid < 26629) {
    int blk = bid - 24581;            // 0..2047
    int bx = blk & 127, by = blk >> 7;
    int tx = threadIdx.x & 31, ty = threadIdx.x >> 5;
    #pragma unroll
    for (int j = 0; j < 32; j += 8)
      tile[ty + j][tx] = d2w[(by * 32 + ty + j) * 4096 + bx * 32 + tx];
    __syncthreads();
    #pragma unroll
    for (int j = 0; j < 32; j += 8)
      d2wTB[(bx * 32 + ty + j) * 512 + by * 32 + tx] = f2bf(tile[tx][ty + j]);
  } else {
    int idx = (bid - 26629) * 256 + threadIdx.x;   // 0..65535
    int row = idx >> 6, lane = threadIdx.x & 63;
    float4 v = *(const float4*)&cbk[row * 256 + lane * 4];
    float s = v.x * v.x + v.y * v.y + v.z * v.z + v.w * v.w;
    #pragma unroll
    for (int m = 1; m < 64; m <<= 1) s += __shfl_xor(s, m);
    if (lane == 0) cbsq[row] = s;
  }
}

// ================ conv1 with fused embedding gather (bf16 MFMA, LDS double-buffered) ================
__global__ __launch_bounds__(256) void k_conv1_embed(const int* __restrict__ tok0,
                                                     const int* __restrict__ tok1,
                                                     const int* __restrict__ tok2,
                                                     const short* __restrict__ embB,
                                                     const short* __restrict__ Wb,
                                                     const float* __restrict__ bias,
                                                     short* __restrict__ Y) {
  __shared__ short sm[2][16896];
  int r0 = blockIdx.y * 128;
  int o0 = blockIdx.x * 128;
  int tid = threadIdx.x;
  int lane = tid & 63, wid = tid >> 6;
  int wm = wid >> 1, wn = wid & 1;
  int ls = lane >> 4, lr = lane & 15;
  int g = ((lane & 3) - ((lane >> 3) & 3)) & 3;

  int toff[3][4];
  #pragma unroll
  for (int i = 0; i < 3; ++i) {
    int q = wid + 4 * i;
    if (q < 9) {
      int rr = r0 - 1 + 16 * q + (lane >> 2);
      bool ok = (rr >= 0) && (rr < NROW);
      int sb = ok ? (rr / 104) : 0;
      int t = rr - sb * 104;
      ok = ok && (t < T_);
      int b = sb & 127, s = sb >> 7;
      const int* tokp = (s == 0) ? tok0 : (s == 1) ? tok1 : tok2;
      if (ok) {
        int4 tv = *(const int4*)&tokp[(b * T_ + t) * CB_];
        toff[i][0] = tv.x * EMB_; toff[i][1] = tv.y * EMB_;
        toff[i][2] = tv.z * EMB_; toff[i][3] = tv.w * EMB_;
      } else {
        toff[i][0] = toff[i][1] = toff[i][2] = toff[i][3] = ZOFF;
      }
    }
  }
  const short* gpw[9];
  #pragma unroll
  for (int i = 0; i < 9; ++i) {
    int q = wid + 4 * i;
    if (q >= 9 && q < 33) {
      int b = q - 9, tap = b >> 3, jj = b & 7;
      gpw[i] = Wb + (long)(tap * 512 + o0 + 16 * jj) * 512 + (long)(lane >> 2) * 512 + g * 8;
    }
  }

  #pragma unroll
  for (int i = 0; i < 3; ++i) {
    int q = wid + 4 * i;
    if (q < 9) GLOAD_LDS(embB + toff[i][0] + g * 8, &sm[0][q * 512]);
  }
  #pragma unroll
  for (int i = 0; i < 9; ++i) {
    int q = wid + 4 * i;
    if (q >= 9 && q < 33) { GLOAD_LDS(gpw[i], &sm[0][q * 512]); gpw[i] += 32; }
  }
  STEP_SYNC();

  f32x4 acc[4][4] = {};
  #pragma unroll
  for (int u = 0; u < 16; ++u) {          // u = cb*4 + kk
    const int cur = u & 1;
    if (u < 15) {
      const int cb2 = (u + 1) >> 2, kk2 = (u + 1) & 3;
      #pragma unroll
      for (int i = 0; i < 3; ++i) {
        int q = wid + 4 * i;
        if (q < 9) GLOAD_LDS(embB + toff[i][cb2] + kk2 * 32 + g * 8, &sm[cur ^ 1][q * 512]);
      }
      #pragma unroll
      for (int i = 0; i < 9; ++i) {
        int q = wid + 4 * i;
        if (q >= 9 && q < 33) { GLOAD_LDS(gpw[i], &sm[cur ^ 1][q * 512]); gpw[i] += 32; }
      }
    }
    const short8* A8 = (const short8*)sm[cur];
    const short8* B8 = (const short8*)(sm[cur] + 4608);
    #pragma unroll
    for (int tap = 0; tap < 3; ++tap) {
      short8 a[4], b[4];
      #pragma unroll
      for (int m = 0; m < 4; ++m) {
        int row = wm * 64 + m * 16 + lr + tap;
        a[m] = A8[row * 4 + SWZ(row, ls)];
      }
      #pragma unroll
      for (int n = 0; n < 4; ++n) {
        int row = wn * 64 + n * 16 + lr;
        b[n] = B8[(tap * 128 + row) * 4 + SWZ(row, ls)];
      }
      #pragma unroll
      for (int m = 0; m < 4; ++m)
        #pragma unroll
        for (int n = 0; n < 4; ++n)
          acc[m][n] = MFMA16(a[m], b[n], acc[m][n]);
    }
    STEP_SYNC();
  }
  #pragma unroll
  for (int m = 0; m < 4; ++m) {
    #pragma unroll
    for (int n = 0; n < 4; ++n) {
      int col = o0 + wn * 64 + n * 16 + lr;
      float bv = bias[col];
      #pragma unroll
      for (int j = 0; j < 4; ++j) {
        int r = r0 + wm * 64 + m * 16 + ls * 4 + j;
        int t = r % TPAD;
        float v = (t < T_) ? fmaxf(acc[m][n][j] + bv, 0.f) : 0.f;
        Y[(long)r * 512 + col] = f2bf(v);
      }
    }
  }
}

// ================ 3-tap conv via bf16 MFMA, LDS double-buffered (conv2) ================
__global__ __launch_bounds__(256) void k_conv3_mfma(const short* __restrict__ X,
                                                    const short* __restrict__ Wb,
                                                    const float* __restrict__ bias,
                                                    short* __restrict__ Y) {
  __shared__ short sm[2][16896];
  int r0 = blockIdx.y * 128;
  int o0 = blockIdx.x * 128;
  int tid = threadIdx.x;
  int lane = tid & 63, wid = tid >> 6;
  int wm = wid >> 1, wn = wid & 1;
  int ls = lane >> 4, lr = lane & 15;
  int g = ((lane & 3) - ((lane >> 3) & 3)) & 3;
  long laneoff = (long)(lane >> 2) * 512 + g * 8;

  const short* gp[9];
  #pragma unroll
  for (int i = 0; i < 9; ++i) {
    int q = wid + 4 * i;
    if (q < 33) {
      long base;
      const short* src;
      if (q < 9) { src = X; base = (long)(r0 - 1 + 16 * q) * 512; }
      else {
        int b = q - 9, tap = b >> 3, j = b & 7;
        src = Wb; base = (long)(tap * 512 + o0 + 16 * j) * 512;
      }
      gp[i] = src + base + laneoff;
    }
  }

  #pragma unroll
  for (int i = 0; i < 9; ++i) {
    int q = wid + 4 * i;
    if (q < 33) { GLOAD_LDS(gp[i], &sm[0][q * 512]); gp[i] += 32; }
  }
  STEP_SYNC();

  f32x4 acc[4][4] = {};
  #pragma unroll
  for (int u = 0; u < 16; ++u) {
    const int cur = u & 1;
    if (u < 15) {
      #pragma unroll
      for (int i = 0; i < 9; ++i) {
        int q = wid + 4 * i;
        if (q < 33) { GLOAD_LDS(gp[i], &sm[cur ^ 1][q * 512]); gp[i] += 32; }
      }
    }
    const short8* A8 = (const short8*)sm[cur];
    const short8* B8 = (const short8*)(sm[cur] + 4608);
    #pragma unroll
    for (int tap = 0; tap < 3; ++tap) {
      short8 a[4], b[4];
      #pragma unroll
      for (int m = 0; m < 4; ++m) {
        int row = wm * 64 + m * 16 + lr + tap;
        a[m] = A8[row * 4 + SWZ(row, ls)];
      }
      #pragma unroll
      for (int n = 0; n < 4; ++n) {
        int row = wn * 64 + n * 16 + lr;
        b[n] = B8[(tap * 128 + row) * 4 + SWZ(row, ls)];
      }
      #pragma unroll
      for (int m = 0; m < 4; ++m)
        #pragma unroll
        for (int n = 0; n < 4; ++n)
          acc[m][n] = MFMA16(a[m], b[n], acc[m][n]);
    }
    STEP_SYNC();
  }
  #pragma unroll
  for (int m = 0; m < 4; ++m) {
    #pragma unroll
    for (int n = 0; n < 4; ++n) {
      int col = o0 + wn * 64 + n * 16 + lr;
      float bv = bias[col];
      #pragma unroll
      for (int j = 0; j < 4; ++j) {
        int r = r0 + wm * 64 + m * 16 + ls * 4 + j;
        int t = r % TPAD;
        float v = (t < T_) ? fmaxf(acc[m][n][j] + bv, 0.f) : 0.f;
        Y[(long)r * 512 + col] = f2bf(v);
      }
    }
  }
}

// ================ bf16 MFMA GEMM (full-K): C = act(A@B^T + bias) ================
__global__ __launch_bounds__(256) void k_gemm_mfma(const short* __restrict__ A,
                                                   const short* __restrict__ B,
                                                   float* __restrict__ C,
                                                   short* __restrict__ Cb,
                                                   const float* __restrict__ bias,
                                                   int K, int N, int relu) {
  __shared__ short sm[8192];
  int r0 = blockIdx.x * 128;
  int o0 = blockIdx.y * 128;
  int tid = threadIdx.x;
  int lane = tid & 63, wid = tid >> 6;
  int wm = wid >> 1, wn = wid & 1;
  int ls = lane >> 4, lr = lane & 15;
  int g = ((lane & 3) - ((lane >> 3) & 3)) & 3;
  long laneoff = (long)(lane >> 2) * K + g * 8;

  const short* gp[4];
  const short* lp[4];
  #pragma unroll
  for (int i = 0; i < 4; ++i) {
    int q = wid + 4 * i;
    const short* src;
    long base;
    if (q < 8) { src = A; base = (long)(r0 + 16 * q) * K; }
    else       { src = B; base = (long)(o0 + 16 * (q - 8)) * K; }
    gp[i] = src + base + laneoff;
    lp[i] = sm + q * 512;
  }

  f32x4 acc[4][4] = {};
  for (int kc = 0; kc < K; kc += 32) {
    __syncthreads();
    #pragma unroll
    for (int i = 0; i < 4; ++i) {
      GLOAD_LDS(gp[i], lp[i]);
      gp[i] += 32;
    }
    __syncthreads();
    const short8* A8 = (const short8*)sm;
    const short8* B8 = (const short8*)(sm + 4096);
    short8 a[4], b[4];
    #pragma unroll
    for (int m = 0; m < 4; ++m) {
      int row = wm * 64 + m * 16 + lr;
      a[m] = A8[row * 4 + SWZ(row, ls)];
    }
    #pragma unroll
    for (int n = 0; n < 4; ++n) {
      int row = wn * 64 + n * 16 + lr;
      b[n] = B8[row * 4 + SWZ(row, ls)];
    }
    #pragma unroll
    for (int m = 0; m < 4; ++m)
      #pragma unroll
      for (int n = 0; n < 4; ++n)
        acc[m][n] = MFMA16(a[m], b[n], acc[m][n]);
  }
  #pragma unroll
  for (int m = 0; m < 4; ++m) {
    #pragma unroll
    for (int n = 0; n < 4; ++n) {
      int col = o0 + wn * 64 + n * 16 + lr;
      float bv = bias ? bias[col] : 0.f;
      #pragma unroll
      for (int j = 0; j < 4; ++j) {
        int r = r0 + wm * 64 + m * 16 + ls * 4 + j;
        float v = acc[m][n][j] + bv;
        if (relu) v = fmaxf(v, 0.f);
        C[(long)r * N + col] = v;
        if (Cb) Cb[(long)r * N + col] = f2bf(v);
      }
    }
  }
}

// ================ dot GEMM + per-tile argmin partials (fused) ================
__global__ __launch_bounds__(256) void k_dot_argmin(const short* __restrict__ A,
                                                    const short* __restrict__ B,
                                                    const float* __restrict__ cbsq,
                                                    float* __restrict__ apv,
                                                    int* __restrict__ api) {
  __shared__ short sm[8192];
  __shared__ float svv[128][2];
  __shared__ int sii[128][2];
  const int K = 256;
  int r0 = blockIdx.x * 128;
  int o0 = blockIdx.y * 128;
  int tid = threadIdx.x;
  int lane = tid & 63, wid = tid >> 6;
  int wm = wid >> 1, wn = wid & 1;
  int ls = lane >> 4, lr = lane & 15;
  int g = ((lane & 3) - ((lane >> 3) & 3)) & 3;
  long laneoff = (long)(lane >> 2) * K + g * 8;

  const short* gp[4];
  const short* lp[4];
  #pragma unroll
  for (int i = 0; i < 4; ++i) {
    int q = wid + 4 * i;
    const short* src;
    long base;
    if (q < 8) { src = A; base = (long)(r0 + 16 * q) * K; }
    else       { src = B; base = (long)(o0 + 16 * (q - 8)) * K; }
    gp[i] = src + base + laneoff;
    lp[i] = sm + q * 512;
  }

  f32x4 acc[4][4] = {};
  #pragma unroll
  for (int kc = 0; kc < K; kc += 32) {
    __syncthreads();
    #pragma unroll
    for (int i = 0; i < 4; ++i) {
      GLOAD_LDS(gp[i], lp[i]);
      gp[i] += 32;
    }
    __syncthreads();
    const short8* A8 = (const short8*)sm;
    const short8* B8 = (const short8*)(sm + 4096);
    short8 a[4], b[4];
    #pragma unroll
    for (int m = 0; m < 4; ++m) {
      int row = wm * 64 + m * 16 + lr;
      a[m] = A8[row * 4 + SWZ(row, ls)];
    }
    #pragma unroll
    for (int n = 0; n < 4; ++n) {
      int row = wn * 64 + n * 16 + lr;
      b[n] = B8[row * 4 + SWZ(row, ls)];
    }
    #pragma unroll
    for (int m = 0; m < 4; ++m)
      #pragma unroll
      for (int n = 0; n < 4; ++n)
        acc[m][n] = MFMA16(a[m], b[n], acc[m][n]);
  }
  // ---- argmin epilogue ----
  float cq[4];
  #pragma unroll
  for (int n = 0; n < 4; ++n) cq[n] = cbsq[o0 + wn * 64 + n * 16 + lr];
  #pragma unroll
  for (int m = 0; m < 4; ++m) {
    #pragma unroll
    for (int j = 0; j < 4; ++j) {
      float bv = 3.4e38f; int bi = 0x7fffffff;
      #pragma unroll
      for (int n = 0; n < 4; ++n) {
        int col = o0 + wn * 64 + n * 16 + lr;
        float v = cq[n] - 2.f * acc[m][n][j];
        if (v < bv || (v == bv && col < bi)) { bv = v; bi = col; }
      }
      #pragma unroll
      for (int d = 1; d < 16; d <<= 1) {
        float ov = __shfl_xor(bv, d);
        int oi = __shfl_xor(bi, d);
        if (ov < bv || (ov == bv && oi < bi)) { bv = ov; bi = oi; }
      }
      if (lr == 0) {
        int rl = wm * 64 + m * 16 + ls * 4 + j;
        svv[rl][wn] = bv;
        sii[rl][wn] = bi;
      }
    }
  }
  __syncthreads();
  if (tid < 128) {
    float v0 = svv[tid][0], v1 = svv[tid][1];
    int i0 = sii[tid][0], i1 = sii[tid][1];
    bool t1 = (v1 < v0) || (v1 == v0 && i1 < i0);
    apv[(long)(r0 + tid) * 8 + blockIdx.y] = t1 ? v1 : v0;
    api[(long)(r0 + tid) * 8 + blockIdx.y] = t1 ? i1 : i0;
  }
}

// ================ VQ combine: 8 partials -> argmin; gather + commit ================
__global__ __launch_bounds__(256) void k_vq_combine(const float* __restrict__ apv,
                                                    const int* __restrict__ api,
                                                    const float* __restrict__ ze,
                                                    const float* __restrict__ cb,
                                                    const short* __restrict__ cbkB,
                                                    short* __restrict__ zallB,
                                                    float* __restrict__ commit_part) {
  __shared__ float sv[256];
  __shared__ int ksb;
  int row = blockIdx.x, tid = threadIdx.x;   // row = s*1024 + b*8 + p
  if (tid == 0) {
    float bv = apv[(long)row * 8]; int bi = api[(long)row * 8];
    #pragma unroll
    for (int j = 1; j < 8; ++j) {
      float v = apv[(long)row * 8 + j]; int i = api[(long)row * 8 + j];
      if (v < bv || (v == bv && i < bi)) { bv = v; bi = i; }
    }
    ksb = bi;
  }
  __syncthreads();
  int ks = ksb;
  float zq = cb[ks * 256 + tid];
  float zev = ze[(long)row * 256 + tid];
  int s = row >> 10, bp = row & 1023;
  int b = bp >> 3, p = bp & 7;
  zallB[b * 6144 + s * 2048 + p * 256 + tid] = cbkB[ks * 256 + tid];
  float d = zev - zq;
  sv[tid] = d * d;
  __syncthreads();
  for (int off = 128; off; off >>= 1) { if (tid < off) sv[tid] += sv[tid + off]; __syncthreads(); }
  if (tid == 0) commit_part[row] = sv[0];
}

// ================ bf16 MFMA split-K stage 1: part[bz][M][N] ================
__global__ __launch_bounds__(256) void k_gemm_mfma_sk(const short* __restrict__ A,
                                                      const short* __restrict__ B,
                                                      float* __restrict__ part,
                                                      int M, int N, int K,
                                                      int kchunk, int KS, long bgstride) {
  __shared__ short sm[8192];
  int r0 = blockIdx.x * 128;
  int o0 = blockIdx.y * 128;
  int bz = blockIdx.z;
  int g = bz / KS, zz = bz - g * KS;
  const short* Bg = B + (long)g * bgstride;
  int k0 = zz * kchunk;
  int tid = threadIdx.x;
  int lane = tid & 63, wid = tid >> 6;
  int wm = wid >> 1, wn = wid & 1;
  int ls = lane >> 4, lr = lane & 15;
  int gsl = ((lane & 3) - ((lane >> 3) & 3)) & 3;
  long laneoff = (long)(lane >> 2) * K + gsl * 8 + k0;

  const short* gp[4];
  const short* lp[4];
  #pragma unroll
  for (int i = 0; i < 4; ++i) {
    int q = wid + 4 * i;
    const short* src;
    long base;
    if (q < 8) { src = A;  base = (long)(r0 + 16 * q) * K; }
    else       { src = Bg; base = (long)(o0 + 16 * (q - 8)) * K; }
    gp[i] = src + base + laneoff;
    lp[i] = sm + q * 512;
  }

  f32x4 acc[4][4] = {};
  for (int kc = 0; kc < kchunk; kc += 32) {
    __syncthreads();
    #pragma unroll
    for (int i = 0; i < 4; ++i) {
      GLOAD_LDS(gp[i], lp[i]);
      gp[i] += 32;
    }
    __syncthreads();
    const short8* A8 = (const short8*)sm;
    const short8* B8 = (const short8*)(sm + 4096);
    short8 a[4], b[4];
    #pragma unroll
    for (int m = 0; m < 4; ++m) {
      int row = wm * 64 + m * 16 + lr;
      a[m] = A8[row * 4 + SWZ(row, ls)];
    }
    #pragma unroll
    for (int n = 0; n < 4; ++n) {
      int row = wn * 64 + n * 16 + lr;
      b[n] = B8[row * 4 + SWZ(row, ls)];
    }
    #pragma unroll
    for (int m = 0; m < 4; ++m)
      #pragma unroll
      for (int n = 0; n < 4; ++n)
        acc[m][n] = MFMA16(a[m], b[n], acc[m][n]);
  }
  float* P = part + (long)bz * M * N;
  #pragma unroll
  for (int m = 0; m < 4; ++m) {
    #pragma unroll
    for (int n = 0; n < 4; ++n) {
      int col = o0 + wn * 64 + n * 16 + lr;
      #pragma unroll
      for (int j = 0; j < 4; ++j) {
        int r = r0 + wm * 64 + m * 16 + ls * 4 + j;
        P[(long)r * N + col] = acc[m][n][j];
      }
    }
  }
}

// ================ split-K stage 2 -> bf16 ================
__global__ void k_reduce_bf16(const float* __restrict__ part, short* __restrict__ Cb,
                              const float* __restrict__ bias, int N, int MN,
                              int KS, int relu, int total4) {
  int id = blockIdx.x * 256 + threadIdx.x;
  if (id >= total4) return;
  int e = id * 4;
  int g = e / MN;
  int rem = e - g * MN;
  const float* base = part + (long)g * KS * MN + rem;
  float4 s = *(const float4*)base;
  for (int j = 1; j < KS; ++j) {
    float4 v = *(const float4*)(base + (long)j * MN);
    s.x += v.x; s.y += v.y; s.z += v.z; s.w += v.w;
  }
  int c = rem % N;
  s.x += bias[c]; s.y += bias[c + 1]; s.z += bias[c + 2]; s.w += bias[c + 3];
  if (relu) {
    s.x = fmaxf(s.x, 0.f); s.y = fmaxf(s.y, 0.f);
    s.z = fmaxf(s.z, 0.f); s.w = fmaxf(s.w, 0.f);
  }
  short4v o;
  o[0] = f2bf(s.x); o[1] = f2bf(s.y); o[2] = f2bf(s.z); o[3] = f2bf(s.w);
  *(short4v*)&Cb[(long)g * MN + rem] = o;
}

// ================ adaptive pool: 13 taps, 1/13 each; bf16 in/out ================
__global__ void k_pool(const short* __restrict__ Xg, short* __restrict__ pooledB) {
  int id = blockIdx.x * 256 + threadIdx.x;   // 3072*64 = 196608 exact
  int row = id >> 6, cg = id & 63;
  int s = row >> 10, bp = row & 1023;
  int b = bp >> 3, p = bp & 7;
  int t0 = (p * 25) >> 1;
  const short8* src = (const short8*)(Xg + (long)((s * 128 + b) * TPAD + t0) * 512) + cg;
  float acc[8] = {};
  #pragma unroll
  for (int j = 0; j < 13; ++j) {
    short8 v = src[j * 64];
    #pragma unroll
    for (int k = 0; k < 8; ++k) acc[k] += bf2f(v[k]);
  }
  short8 o;
  #pragma unroll
  for (int k = 0; k < 8; ++k) o[k] = f2bf(acc[k] * (1.f / 13.f));
  ((short8*)pooledB)[(long)row * 64 + cg] = o;
}

// ================ fused: logits-partials reduce + logsumexp + NLL gather ================
__global__ __launch_bounds__(256) void k_logits_lse_recon(const float* __restrict__ part,
                                                          const float* __restrict__ d2b,
                                                          const int* __restrict__ tok,
                                                          float* __restrict__ rpart2) {
  __shared__ float row[1024];
  __shared__ float sm[256];
  int blk = blockIdx.x;
  int cb_i = blk & 3, b = (blk >> 2) & 127, cls = blk >> 9;
  int m = cls * 128 + b;
  const float* p0 = part + (long)m * 4096 + cb_i * 1024;
  const float* p1 = p0 + (long)384 * 4096;
  const float* bb = d2b + cb_i * 1024;
  int tid = threadIdx.x;
  float v[4];
  #pragma unroll
  for (int j = 0; j < 4; ++j) {
    int c = tid + 256 * j;
    v[j] = p0[c] + p1[c] + bb[c];
    row[c] = v[j];
  }
  float mx = fmaxf(fmaxf(v[0], v[1]), fmaxf(v[2], v[3]));
  sm[tid] = mx; __syncthreads();
  for (int off = 128; off; off >>= 1) { if (tid < off) sm[tid] = fmaxf(sm[tid], sm[tid + off]); __syncthreads(); }
  float gm = sm[0]; __syncthreads();
  float e = expf(v[0] - gm) + expf(v[1] - gm) + expf(v[2] - gm) + expf(v[3] - gm);
  sm[tid] = e; __syncthreads();
  for (int off = 128; off; off >>= 1) { if (tid < off) sm[tid] += sm[tid + off]; __syncthreads(); }
  float lse = gm + logf(sm[0]);
  __syncthreads();
  float val = 0.f;
  if (cls == 1) {
    if (tid < 98) {
      int tk = tok[(b * T_ + tid + 1) * CB_ + cb_i];
      val = lse - row[tk];
    }
  } else if (tid == 0) {
    int t = (cls == 0) ? 0 : 99;
    int tk = tok[(b * T_ + t) * CB_ + cb_i];
    val = lse - row[tk];
  }
  sm[tid] = val; __syncthreads();
  for (int off = 128; off; off >>= 1) { if (tid < off) sm[tid] += sm[tid + off]; __syncthreads(); }
  if (tid == 0) rpart2[blk] = sm[0];
}

// ================ final ================
__global__ void k_final(const float* __restrict__ rpart2, const float* __restrict__ cpart,
                        float* __restrict__ out) {
  __shared__ float sm[256];
  __shared__ float rs;
  int tid = threadIdx.x;
  float r = 0.f;
  #pragma unroll
  for (int j = 0; j < 6; ++j) r += rpart2[tid + 256 * j];
  sm[tid] = r; __syncthreads();
  for (int off = 128; off; off >>= 1) { if (tid < off) sm[tid] += sm[tid + off]; __syncthreads(); }
  if (tid == 0) rs = sm[0];
  __syncthreads();
  float c = 0.f;
  #pragma unroll
  for (int j = 0; j < 12; ++j) c += cpart[tid + 256 * j];
  sm[tid] = c; __syncthreads();
  for (int off = 128; off; off >>= 1) { if (tid < off) sm[tid] += sm[tid + off]; __syncthreads(); }
  if (tid == 0) out[0] = rs / 51200.f + 0.1f * (sm[0] / 262144.f);
}

extern "C" void kernel_launch(void* const* d_in, const int* in_sizes, int n_in,
                              void* d_out, int out_size, void* d_ws, size_t ws_size,
                              hipStream_t stream) {
  const int*   tok_prev = (const int*)d_in[0];
  const int*   tok_curr = (const int*)d_in[1];
  const int*   tok_next = (const int*)d_in[2];
  const float* emb  = (const float*)d_in[3];
  const float* c1w  = (const float*)d_in[4];
  const float* c1b  = (const float*)d_in[5];
  const float* c2w  = (const float*)d_in[6];
  const float* c2b  = (const float*)d_in[7];
  const float* c3w  = (const float*)d_in[8];
  const float* c3b  = (const float*)d_in[9];
  const float* cbk  = (const float*)d_in[10];
  const float* fc1w = (const float*)d_in[11];
  const float* fc1b = (const float*)d_in[12];
  const float* fc2w = (const float*)d_in[13];
  const float* fc2b = (const float*)d_in[14];
  const float* d1w  = (const float*)d_in[15];
  const float* d1b  = (const float*)d_in[16];
  const float* d2w  = (const float*)d_in[17];
  const float* d2b  = (const float*)d_in[18];

  // ---- workspace layout (f32 word offsets) ----
  float* ws = (float*)d_ws;
  short* XbS = (short*)ws;                          // conv2 output (bf16)
  short* YbS = (short*)(ws + 10224128);             // conv1 output, guard rows
  float* fp  = ws + 2 * 10224128;
  short* Wb1    = (short*)fp;                       //   393,216 w
  short* Wb2    = (short*)(fp + 393216);            //   393,216 w
  short* c3wB   = (short*)(fp + 786432);            //    65,536 w
  short* cbkB   = (short*)(fp + 851968);            //   131,072 w
  short* pooledB= (short*)(fp + 983040);            //   786,432 w
  float* ze     = fp + 1769472;                     //   786,432 w
  short* zeB    = (short*)(fp + 2555904);           //   393,216 w
  short* fc1wB  = (short*)(fp + 2949120);           // 1,572,864 w
  short* fc2wB  = (short*)(fp + 4521984);           //   131,072 w
  short* SB     = (short*)(fp + 4653056);           //   393,216 w
  short* d2wTB  = (short*)(fp + 5046272);           // 1,048,576 w
  float* part   = fp + 6094848;                     // 3,145,728 w (split-K partials)
  float* cbsq   = part + 3145728;                   //     1,024
  short* zallB  = (short*)(cbsq + 1024);            //   393,216 w
  float* cpart  = cbsq + 1024 + 393216;             //     3,072
  short* h1B    = (short*)(cpart + 3072);           //    32,768 w
  short* h2B    = (short*)(cpart + 35840);          //    32,768 w
  short* h2cB   = (short*)(cpart + 68608);          //    98,304 w
  float* rpart2 = cpart + 166912;                   //     1,536
  float* apv    = cpart + 168448;                   //    24,576
  int*   api    = (int*)(cpart + 193024);           //    24,576
  short* embB   = (short*)(cpart + 217600);         //    65,600 w
  // total ~30.4M words ~121.5 MB

  const short* Yv = YbS + 512;    // conv1 output rows, row -1 = guard
  short* Xc = XbS + 512;          // conv2 output rows

  // ---- prep ----
  k_prep<<<26885, 256, 0, stream>>>(emb, c1w, c2w, c3w, cbk, fc1w, fc2w, d1w, d2w,
                                    YbS, embB, Wb1, Wb2, c3wB, cbkB, fc1wB, fc2wB,
                                    SB, d2wTB, cbsq);

  // ---- encoder (all 3 segments batched) ----
  k_conv1_embed<<<dim3(4, 312), 256, 0, stream>>>(tok_prev, tok_curr, tok_next,
                                                  embB, Wb1, c1b, (short*)Yv);
  k_conv3_mfma <<<dim3(4, 312), 256, 0, stream>>>(Yv, Wb2, c2b, Xc);
  k_pool       <<<768, 256, 0, stream>>>(Xc, pooledB);
  k_gemm_mfma  <<<dim3(24, 2), 256, 0, stream>>>(pooledB, c3wB, ze, zeB, c3b, 512, 256, 0);
  k_dot_argmin <<<dim3(24, 8), 256, 0, stream>>>(zeB, cbkB, cbsq, apv, api);
  k_vq_combine <<<3072, 256, 0, stream>>>(apv, api, ze, cbk, cbkB, zallB, cpart);

  // ---- decoder: bf16 MFMA split-K ----
  k_gemm_mfma_sk<<<dim3(1, 4, 16), 256, 0, stream>>>(zallB, fc1wB, part, 128, 512, 6144, 384, 16, 0);
  k_reduce_bf16 <<<64, 256, 0, stream>>>(part, h1B, fc1b, 512, 65536, 16, 1, 16384);
  k_gemm_mfma_sk<<<dim3(1, 4, 8), 256, 0, stream>>>(h1B, fc2wB, part, 128, 512, 512, 64, 8, 0);
  k_reduce_bf16 <<<64, 256, 0, stream>>>(part, h2B, fc2b, 512, 65536, 8, 1, 16384);
  k_gemm_mfma_sk<<<dim3(1, 4, 24), 256, 0, stream>>>(h2B, SB, part, 128, 512, 512, 64, 8, 262144);
  k_reduce_bf16 <<<192, 256, 0, stream>>>(part, h2cB, d1b, 512, 65536, 8, 1, 49152);
  k_gemm_mfma_sk<<<dim3(3, 32, 2), 256, 0, stream>>>(h2cB, d2wTB, part, 384, 4096, 512, 256, 2, 0);
  k_logits_lse_recon<<<1536, 256, 0, stream>>>(part, d2b, tok_curr, rpart2);

  k_final<<<1, 256, 0, stream>>>(rpart2, cpart, (float*)d_out);
}